// Round 1
// 292.509 us; speedup vs baseline: 1.1095x; 1.1095x over previous
//
#include <hip/hip_runtime.h>
#include <hip/hip_bf16.h>
#include <stdint.h>

// ---------- types ----------
typedef __bf16 v8bf __attribute__((ext_vector_type(8)));
typedef float  v4f  __attribute__((ext_vector_type(4)));

__device__ __forceinline__ ushort f2bf(float f) {
    union { float f; uint32_t u; } x; x.f = f;
    uint32_t r = (x.u + 0x7FFFu + ((x.u >> 16) & 1u)) >> 16;
    return (ushort)r;
}
// pack two non-negative floats to bf16x2 (round-half-up): 2 add + 1 v_perm
__device__ __forceinline__ uint32_t pack2bf(float a, float b) {
    union { float f; uint32_t u; } xa, xb; xa.f = a; xb.f = b;
    return __builtin_amdgcn_perm(xb.u + 0x8000u, xa.u + 0x8000u, 0x07060302u);
}

__device__ __forceinline__ void load_lds16(const void* g, void* l) {
    __builtin_amdgcn_global_load_lds(
        (const __attribute__((address_space(1))) uint32_t*)g,
        (__attribute__((address_space(3))) uint32_t*)l, 16, 0, 0);
}

// ---------- elementwise convert ----------
__global__ void cvt_f32_bf16_k(const float4* __restrict__ src,
                               ushort* __restrict__ dst, int n4) {
    int i = blockIdx.x * 256 + threadIdx.x;
    if (i >= n4) return;
    float4 f = src[i];
    ushort4 u = make_ushort4(f2bf(f.x), f2bf(f.y), f2bf(f.z), f2bf(f.w));
    *(ushort4*)(dst + 4 * (size_t)i) = u;
}

// ---------- fused LDS-tiled transpose+convert for all 4 weights ----------
__global__ __launch_bounds__(256) void transpose_all(
    const float* __restrict__ Wq, const float* __restrict__ Wk,
    const float* __restrict__ Wv, const float* __restrict__ Wo,
    ushort* __restrict__ wqk_t, ushort* __restrict__ wv_t,
    ushort* __restrict__ wo_t) {
    __shared__ ushort tile[64][65];
    const int tid = threadIdx.x;
    const int ix = blockIdx.x, k0 = blockIdx.y * 64;
    const float* src; ushort* dst; int N, n0;
    if (ix < 32)      { src = Wq; dst = wqk_t;                       N = 2048; n0 = ix * 64; }
    else if (ix < 40) { src = Wk; dst = wqk_t + (size_t)2048 * 2048; N = 512;  n0 = (ix - 32) * 64; }
    else if (ix < 48) { src = Wv; dst = wv_t;                        N = 512;  n0 = (ix - 40) * 64; }
    else              { src = Wo; dst = wo_t;                        N = 2048; n0 = (ix - 48) * 64; }
    const int nn = tid & 63, kb = tid >> 6;
#pragma unroll
    for (int p = 0; p < 16; ++p) {
        int kk = p * 4 + kb;
        tile[kk][nn] = f2bf(src[(size_t)(k0 + kk) * N + n0 + nn]);
    }
    __syncthreads();
    const int nr = tid >> 2, kch = (tid & 3) * 16;
    union { ushort u[16]; uint4 q[2]; } tmp;
#pragma unroll
    for (int j = 0; j < 16; ++j) tmp.u[j] = tile[kch + j][nr];
    uint4* out = (uint4*)&dst[(size_t)(n0 + nr) * 2048 + k0 + kch];
    out[0] = tmp.q[0];
    out[1] = tmp.q[1];
}

// ---------- GEMM core (m97 structure), K = 2048 ----------
template <bool OUT_BF16>
__device__ __forceinline__ void gemm_body(
    const ushort* __restrict__ A, const ushort* __restrict__ Bt,
    void* __restrict__ Cout, int K, int ldc, int m0, int n0,
    ushort* As, ushort* Bs) {
    const int tid  = threadIdx.x;
    const int wave = tid >> 6, lane = tid & 63;
    const int wr = wave >> 1, wc = wave & 1;
    const int mq = lane & 15, quad = lane >> 4;

    v4f acc[4][4] = {};

    for (int k0 = 0; k0 < K; k0 += 32) {
#pragma unroll
        for (int i = 0; i < 2; ++i) {
            const int off = wave * 2048 + i * 1024 + lane * 16;
            const int row = off >> 6;
            const int ce  = (off & 63) >> 1;
            load_lds16(A  + (size_t)(m0 + row) * K + k0 + ce, As + wave * 1024 + i * 512);
            load_lds16(Bt + (size_t)(n0 + row) * K + k0 + ce, Bs + wave * 1024 + i * 512);
        }
        __syncthreads();
        v8bf af[4], bfr[4];
#pragma unroll
        for (int mt = 0; mt < 4; ++mt)
            af[mt] = *(const v8bf*)(As + (wr * 64 + mt * 16 + mq) * 32 + quad * 8);
#pragma unroll
        for (int nt = 0; nt < 4; ++nt)
            bfr[nt] = *(const v8bf*)(Bs + (wc * 64 + nt * 16 + mq) * 32 + quad * 8);
#pragma unroll
        for (int mt = 0; mt < 4; ++mt)
#pragma unroll
            for (int nt = 0; nt < 4; ++nt)
                acc[mt][nt] = __builtin_amdgcn_mfma_f32_16x16x32_bf16(
                    af[mt], bfr[nt], acc[mt][nt], 0, 0, 0);
        __syncthreads();
    }

#pragma unroll
    for (int mt = 0; mt < 4; ++mt) {
        const int r = m0 + wr * 64 + mt * 16 + quad * 4;
#pragma unroll
        for (int nt = 0; nt < 4; ++nt) {
            const int c = n0 + wc * 64 + nt * 16 + mq;
#pragma unroll
            for (int reg = 0; reg < 4; ++reg) {
                if (OUT_BF16)
                    ((ushort*)Cout)[(size_t)(r + reg) * ldc + c] = f2bf(acc[mt][nt][reg]);
                else
                    ((float*)Cout)[(size_t)(r + reg) * ldc + c] = acc[mt][nt][reg];
            }
        }
    }
}

// fused QK-projection (640 blocks) + V^T-projection (128 blocks)
__global__ __launch_bounds__(256) void gemm_qkv(
    const ushort* __restrict__ xb, const ushort* __restrict__ wqk_t,
    const ushort* __restrict__ wv_t, ushort* __restrict__ qkb,
    ushort* __restrict__ vtb) {
    __shared__ __align__(16) ushort As[128 * 32];
    __shared__ __align__(16) ushort Bs[128 * 32];
    int bid = blockIdx.x;
    if (bid < 640) {   // qkb[M=4096][N=2560] = xb * wqk_t^T
        gemm_body<true>(xb, wqk_t, qkb, 2048, 2560,
                        (bid / 20) * 128, (bid % 20) * 128, As, Bs);
    } else {           // vtb[M=512][N=4096] = wv_t * xb^T
        bid -= 640;
        gemm_body<true>(wv_t, xb, vtb, 2048, 4096,
                        (bid >> 5) * 128, (bid & 31) * 128, As, Bs);
    }
}

// output projection: d_out[4096][2048] f32 = attn_out * wo_t^T
__global__ __launch_bounds__(256) void gemm_out(
    const ushort* __restrict__ A, const ushort* __restrict__ Bt,
    float* __restrict__ C) {
    __shared__ __align__(16) ushort As[128 * 32];
    __shared__ __align__(16) ushort Bs[128 * 32];
    gemm_body<false>(A, Bt, C, 2048, 2048,
                     blockIdx.y * 128, blockIdx.x * 128, As, Bs);
}

// ---------- flash attention v7: 2 q-groups/wave (32 rows), 64-kv tiles ----------
// Rationale: v6 was LDS-BW-bound (each wave re-reads the whole K/V tile per 16
// q-rows). Each kb/vb fragment now feeds 2 MFMAs -> LDS read bytes per unit of
// work halved.
constexpr int LDK = 72, LDV = 72;
constexpr float SC2 = 0.18033688011f;   // 0.125 * log2(e)
constexpr float MB2 = 14.4269504089f;   // 10 * log2(e)  (fixed softmax max M=10, exact)

template <bool MASK>
__device__ __forceinline__ void attn_compute(
    int kv0, int qrow, int mq, int quad, int lane_lo,
    const ushort* Ks, const ushort* Vs, const v8bf ones,
    const v8bf (&qf)[2][2], v4f (&oacc)[2][4], v4f (&osum)[2]) {
    const bool hi = quad >= 2;
    // process two nt-halves; each half = 32 kv columns of P and one PV K-slice
#pragma unroll
    for (int half = 0; half < 2; ++half) {
        uint32_t pk[2][2][2];   // [group][nt-within-half][dword]
#pragma unroll
        for (int ntl = 0; ntl < 2; ++ntl) {
            const int nt = 2 * half + ntl;
            v4f sacc[2] = {{0.f,0.f,0.f,0.f}, {0.f,0.f,0.f,0.f}};
            // S^T = K * Q^T : C row = kv (quad*4+reg), col = q (mq); kb reused for both groups
#pragma unroll
            for (int ks = 0; ks < 2; ++ks) {
                v8bf kb = *(const v8bf*)&Ks[(nt * 16 + mq) * LDK + ks * 32 + quad * 8];
                sacc[0] = __builtin_amdgcn_mfma_f32_16x16x32_bf16(kb, qf[0][ks], sacc[0], 0, 0, 0);
                sacc[1] = __builtin_amdgcn_mfma_f32_16x16x32_bf16(kb, qf[1][ks], sacc[1], 0, 0, 0);
            }
#pragma unroll
            for (int g = 0; g < 2; ++g) {
                float pr[4];
#pragma unroll
                for (int reg = 0; reg < 4; ++reg) {
                    float s = sacc[g][reg];
                    if (MASK) {
                        const int kv = kv0 + nt * 16 + quad * 4 + reg;
                        const int q  = qrow + 16 * g + mq;
                        if (kv > q) s = -3.0e38f;
                    }
                    pr[reg] = __builtin_amdgcn_exp2f(fmaf(s, SC2, -MB2));
                }
                pk[g][ntl][0] = pack2bf(pr[0], pr[1]);
                pk[g][ntl][1] = pack2bf(pr[2], pr[3]);
            }
        }
        // P C-layout -> A-layout via cross-quad shuffles (no LDS round-trip)
        v8bf pf[2];
#pragma unroll
        for (int g = 0; g < 2; ++g) {
            uint32_t a0 = __shfl(pk[g][0][0], lane_lo);
            uint32_t b0 = __shfl(pk[g][1][0], lane_lo);
            uint32_t a1 = __shfl(pk[g][0][1], lane_lo);
            uint32_t b1 = __shfl(pk[g][1][1], lane_lo);
            uint32_t a2 = __shfl(pk[g][0][0], lane_lo + 16);
            uint32_t b2 = __shfl(pk[g][1][0], lane_lo + 16);
            uint32_t a3 = __shfl(pk[g][0][1], lane_lo + 16);
            uint32_t b3 = __shfl(pk[g][1][1], lane_lo + 16);
            union { uint32_t d[4]; v8bf v; } u;
            u.d[0] = hi ? b0 : a0;
            u.d[1] = hi ? b1 : a1;
            u.d[2] = hi ? b2 : a2;
            u.d[3] = hi ? b3 : a3;
            pf[g] = u.v;
            // row-sums via MFMA with constant all-ones B (lands in C-layout = oacc layout)
            osum[g] = __builtin_amdgcn_mfma_f32_16x16x32_bf16(pf[g], ones, osum[g], 0, 0, 0);
        }
        // PV: vb reused for both groups
#pragma unroll
        for (int hdt = 0; hdt < 4; ++hdt) {
            v8bf vb = *(const v8bf*)&Vs[(hdt * 16 + mq) * LDV + half * 32 + quad * 8];
            oacc[0][hdt] = __builtin_amdgcn_mfma_f32_16x16x32_bf16(pf[0], vb, oacc[0][hdt], 0, 0, 0);
            oacc[1][hdt] = __builtin_amdgcn_mfma_f32_16x16x32_bf16(pf[1], vb, oacc[1][hdt], 0, 0, 0);
        }
    }
}

// qkb: [B*T][2560] bf16 (Q|K); vt: [512][4096] bf16 ([g*64+hd][b*2048+t]); out: [B*T][2048] bf16
// 256 threads / 4 waves / 128-row q-tiles (32 rows = 2 groups per wave) / 64-kv tiles.
// LDS 18.4 KB; VGPR capped at 128 -> 4 blocks/CU (grid = 1024 = exactly 4/CU).
__global__ __launch_bounds__(256, 4) void attn_fwd(
    const ushort* __restrict__ qkb, const ushort* __restrict__ vt,
    ushort* __restrict__ outp) {
    __shared__ __align__(16) ushort Ks[64 * LDK];   // 9216 B
    __shared__ __align__(16) ushort Vs[64 * LDV];   // 9216 B

    const int tid  = threadIdx.x;
    const int wave = tid >> 6, lane = tid & 63;
    const int mq = lane & 15, quad = lane >> 4;
    const int lane_lo = (quad & 1) * 32 + mq;
    const int h = blockIdx.y, b = blockIdx.z;
    const int g = h >> 2;
    // balance: CU c gets blocks {b0:(x,h),(x,h+16), b1: same} -> qt and 15-qt pair per CU
    const int base = (blockIdx.x + h) & 15;
    const int qt   = b ? (15 - base) : base;
    const int qb0  = qt * 128;
    const int qrow = qb0 + wave * 32;   // this wave's first q-row (2 groups: qrow, qrow+16)

    union { ushort u[8]; v8bf v; } one_u;
#pragma unroll
    for (int i = 0; i < 8; ++i) one_u.u[i] = 0x3F80;   // bf16 1.0
    const v8bf ones = one_u.v;

    v8bf qf[2][2];
#pragma unroll
    for (int gg = 0; gg < 2; ++gg) {
        const ushort* qp = qkb + (size_t)(b * 2048 + qrow + 16 * gg + mq) * 2560 + h * 64 + quad * 8;
        qf[gg][0] = *(const v8bf*)qp;
        qf[gg][1] = *(const v8bf*)(qp + 32);
    }

    v4f oacc[2][4] = {};
    v4f osum[2] = {};

    const ushort* kg = qkb + (size_t)(b * 2048) * 2560 + 2048 + g * 64;
    const ushort* vg = vt + (size_t)(g * 64) * 4096 + b * 2048;

    // staging decomposition (256 threads, 2 chunks each for K and V)
    const int krow0 = tid >> 3,  kch = (tid & 7) * 8;   // rows 0..31
    const int krow1 = krow0 + 32;
    const int vrow0 = tid >> 3;                          // V^T rows (hd) 0..31
    const int vrow1 = vrow0 + 32;

    const int ntiles = 2 * qt + 2;
    uint4 kr0, kr1, vr0, vr1;
    {   // prefetch tile 0
        kr0 = *(const uint4*)(kg + (size_t)krow0 * 2560 + kch);
        kr1 = *(const uint4*)(kg + (size_t)krow1 * 2560 + kch);
        vr0 = *(const uint4*)(vg + (size_t)vrow0 * 4096 + kch);
        vr1 = *(const uint4*)(vg + (size_t)vrow1 * 4096 + kch);
    }

#pragma unroll 1
    for (int j = 0; j < ntiles; ++j) {
        const int kv0 = j * 64;
        __syncthreads();   // previous tile's LDS reads done
        *(uint4*)&Ks[krow0 * LDK + kch] = kr0;
        *(uint4*)&Ks[krow1 * LDK + kch] = kr1;
        *(uint4*)&Vs[vrow0 * LDV + kch] = vr0;
        *(uint4*)&Vs[vrow1 * LDV + kch] = vr1;
        __syncthreads();
        if (j + 1 < ntiles) {   // prefetch next tile (hidden behind compute)
            const int nk = kv0 + 64;
            kr0 = *(const uint4*)(kg + (size_t)(nk + krow0) * 2560 + kch);
            kr1 = *(const uint4*)(kg + (size_t)(nk + krow1) * 2560 + kch);
            vr0 = *(const uint4*)(vg + (size_t)vrow0 * 4096 + nk + kch);
            vr1 = *(const uint4*)(vg + (size_t)vrow1 * 4096 + nk + kch);
        }
        // kv0 - qrow is a multiple of 32 -> both groups active iff kv0 <= qrow;
        // both need masking iff kv0 + 64 > qrow (exactly one such tile per wave).
        if (kv0 <= qrow) {
            if (kv0 + 64 > qrow)
                attn_compute<true>(kv0, qrow, mq, quad, lane_lo, Ks, Vs, ones, qf, oacc, osum);
            else
                attn_compute<false>(kv0, qrow, mq, quad, lane_lo, Ks, Vs, ones, qf, oacc, osum);
        }
    }

    // normalize: osum is in C-layout identical to oacc (row m = quad*4+reg) — no shuffles
#pragma unroll
    for (int gg = 0; gg < 2; ++gg) {
#pragma unroll
        for (int reg = 0; reg < 4; ++reg) {
            const float invr = 1.0f / osum[gg][reg];
            const int rr = qrow + 16 * gg + quad * 4 + reg;
#pragma unroll
            for (int hdt = 0; hdt < 4; ++hdt)
                outp[(size_t)(b * 2048 + rr) * 2048 + h * 64 + hdt * 16 + mq] =
                    f2bf(oacc[gg][hdt][reg] * invr);
        }
    }
}

// ---------- launch ----------
extern "C" void kernel_launch(void* const* d_in, const int* in_sizes, int n_in,
                              void* d_out, int out_size, void* d_ws, size_t ws_size,
                              hipStream_t stream) {
    const float* x  = (const float*)d_in[0];
    const float* Wq = (const float*)d_in[1];
    const float* Wk = (const float*)d_in[2];
    const float* Wv = (const float*)d_in[3];
    const float* Wo = (const float*)d_in[4];

    char* ws = (char*)d_ws;
    ushort* xb    = (ushort*)(ws);                  // [4096][2048] x bf16; later attn output
    ushort* wqk_t = (ushort*)(ws + 16777216);       // [2560][2048]
    ushort* wv_t  = (ushort*)(ws + 27262976);       // [512][2048]
    ushort* wo_t  = (ushort*)(ws + 29360128);       // [2048][2048]
    ushort* qkb   = (ushort*)(ws + 37748736);       // [4096][2560]  Q|K
    ushort* vtb   = (ushort*)(ws + 58720256);       // [512][4096]   V^T

    cvt_f32_bf16_k<<<8192, 256, 0, stream>>>((const float4*)x, xb, 2097152);
    transpose_all<<<dim3(80, 32), 256, 0, stream>>>(Wq, Wk, Wv, Wo, wqk_t, wv_t, wo_t);

    gemm_qkv<<<768, 256, 0, stream>>>(xb, wqk_t, wv_t, qkb, vtb);
    attn_fwd<<<dim3(16, 32, 2), 256, 0, stream>>>(qkb, vtb, xb);
    gemm_out<<<dim3(16, 32), 256, 0, stream>>>(xb, wo_t, (float*)d_out);
}